// Round 1
// baseline (1561.572 us; speedup 1.0000x reference)
//
#include <hip/hip_runtime.h>
#include <hip/hip_bf16.h>
#include <math.h>

#define N_ATOMS 524288
#define DIM 256
#define NB 16384          // number of molecules / segments
#define M_STEPS 6

typedef short bf16x8 __attribute__((ext_vector_type(8)));
typedef float f32x16 __attribute__((ext_vector_type(16)));

__device__ __forceinline__ unsigned short f2bf(float f) {
    union { float f; unsigned u; } x; x.f = f;
    unsigned r = x.u + 0x7FFFu + ((x.u >> 16) & 1u);   // round-nearest-even
    return (unsigned short)(r >> 16);
}
__device__ __forceinline__ float sigmoidf_(float z) {
    return 1.0f / (1.0f + __expf(-z));
}
// tanh via hw exp: exact at +-inf, ~1e-6 rel error, ~4 instrs vs ~25 for libm tanhf
__device__ __forceinline__ float tanh_fast(float z) {
    return 1.0f - 2.0f / (__expf(2.0f * z) + 1.0f);
}

// ---------------------------------------------------------------------------
// Kernel 1: segment bounds via binary search (atom_split is sorted)
// ---------------------------------------------------------------------------
__global__ void bounds_kernel(const int* __restrict__ split, int* __restrict__ lb) {
    int b = blockIdx.x * blockDim.x + threadIdx.x;
    if (b > NB) return;
    int lo = 0, hi = N_ATOMS;
    while (lo < hi) {
        int mid = (lo + hi) >> 1;
        if (split[mid] < b) lo = mid + 1; else hi = mid;
    }
    lb[b] = lo;
}

// ---------------------------------------------------------------------------
// Kernel 2: pre-swizzle U (f32 [512,1024]) into bf16 B-fragment order for
// mfma_f32_32x32x16_bf16. (unchanged, verified)
// ---------------------------------------------------------------------------
__global__ __launch_bounds__(256) void uswz_kernel(const float* __restrict__ U,
                                                   unsigned short* __restrict__ ubf) {
    int d = blockIdx.x * 256 + threadIdx.x;
    int f = d >> 8;
    int r = d & 255;
    int jjp = r >> 6;
    int lane = r & 63;
    int nt = f >> 5, kc = f & 31;
    int n = nt * 32 + (lane & 31);
    int k = kc * 16 + (lane >> 5) * 8 + jjp * 2;
    unsigned short b0 = f2bf(U[(size_t)k * 1024 + n]);
    unsigned short b1 = f2bf(U[(size_t)(k + 1) * 1024 + n]);
    ushort2 p; p.x = b0; p.y = b1;
    *(ushort2*)(&ubf[(size_t)(f * 64 + lane) * 8 + jjp * 2]) = p;
}

// ---------------------------------------------------------------------------
// Kernel 3: fused segment attention, 4 atoms per wave per iteration.
// One WAVE per segment (4 segments per 256-thread block). Lane (g,q):
// g = lane>>4 owns atom s+g, s+g+4, ...; q = lane&15 owns dims [16q,16q+16).
// Butterfly masks 1,2,4,8 reduce all 4 atoms' dots at once; masks 16,32
// combine the 4 atom-groups once at the end. No LDS, no barriers.
// ---------------------------------------------------------------------------
__global__ __launch_bounds__(256) void attn_kernel(
    const float* __restrict__ x,      // [N_ATOMS, DIM]
    const int* __restrict__ lb,       // [NB+1]
    const float* __restrict__ h,      // [NB, DIM]
    float* __restrict__ rout,         // output base
    int rstride)                      // row stride of rout
{
    const int t    = threadIdx.x;
    const int wave = t >> 6;
    const int lane = t & 63;
    const int b    = blockIdx.x * 4 + wave;
    const int g    = lane >> 4;       // atom subgroup 0..3
    const int q    = lane & 15;       // dim subgroup 0..15

    const int s = lb[b];
    const int e = lb[b + 1];

    // h fragment: 16 floats/lane; same addr across the 4 groups -> line-coalesced
    const float* hrow = &h[(size_t)b * DIM + q * 16];
    const float4 hv0 = *(const float4*)(hrow + 0);
    const float4 hv1 = *(const float4*)(hrow + 4);
    const float4 hv2 = *(const float4*)(hrow + 8);
    const float4 hv3 = *(const float4*)(hrow + 12);

    float a0x=0.f,a0y=0.f,a0z=0.f,a0w=0.f;
    float a1x=0.f,a1y=0.f,a1z=0.f,a1w=0.f;
    float a2x=0.f,a2y=0.f,a2z=0.f,a2w=0.f;
    float a3x=0.f,a3y=0.f,a3z=0.f,a3w=0.f;
    float ssum = 0.f;

    int i = s + g;
    float4 c0 = {0.f,0.f,0.f,0.f}, c1 = {0.f,0.f,0.f,0.f};
    float4 c2 = {0.f,0.f,0.f,0.f}, c3 = {0.f,0.f,0.f,0.f};
    if (i < e) {
        const float* xr = &x[(size_t)i * DIM + q * 16];
        c0 = *(const float4*)(xr + 0);
        c1 = *(const float4*)(xr + 4);
        c2 = *(const float4*)(xr + 8);
        c3 = *(const float4*)(xr + 12);
    }
    while (i < e) {
        // ---- 1-deep software pipeline: issue next-iter loads first ----
        const int inext = i + 4;
        const int iload = (inext < e) ? inext : i;   // clamp: always a valid row
        const float* xr = &x[(size_t)iload * DIM + q * 16];
        const float4 n0 = *(const float4*)(xr + 0);
        const float4 n1 = *(const float4*)(xr + 4);
        const float4 n2 = *(const float4*)(xr + 8);
        const float4 n3 = *(const float4*)(xr + 12);

        // ---- dot partial over this lane's 16 dims (balanced tree) ----
        float d01 = c0.x*hv0.x + c0.y*hv0.y + c0.z*hv0.z + c0.w*hv0.w
                  + c1.x*hv1.x + c1.y*hv1.y + c1.z*hv1.z + c1.w*hv1.w;
        float d23 = c2.x*hv2.x + c2.y*hv2.y + c2.z*hv2.z + c2.w*hv2.w
                  + c3.x*hv3.x + c3.y*hv3.y + c3.z*hv3.z + c3.w*hv3.w;
        float d = d01 + d23;
        // reduce within each 16-lane group (handles all 4 atoms at once)
        d += __shfl_xor(d, 1, 64);
        d += __shfl_xor(d, 2, 64);
        d += __shfl_xor(d, 4, 64);
        d += __shfl_xor(d, 8, 64);
        const float ee = __expf(d);
        ssum += ee;
        a0x += ee*c0.x; a0y += ee*c0.y; a0z += ee*c0.z; a0w += ee*c0.w;
        a1x += ee*c1.x; a1y += ee*c1.y; a1z += ee*c1.z; a1w += ee*c1.w;
        a2x += ee*c2.x; a2y += ee*c2.y; a2z += ee*c2.z; a2w += ee*c2.w;
        a3x += ee*c3.x; a3y += ee*c3.y; a3z += ee*c3.z; a3w += ee*c3.w;

        c0 = n0; c1 = n1; c2 = n2; c3 = n3;
        i = inext;
    }

    // ---- combine the 4 atom-groups (lanes reconverged here) ----
#define XRED(v) { v += __shfl_xor(v, 16, 64); v += __shfl_xor(v, 32, 64); }
    XRED(a0x) XRED(a0y) XRED(a0z) XRED(a0w)
    XRED(a1x) XRED(a1y) XRED(a1z) XRED(a1w)
    XRED(a2x) XRED(a2y) XRED(a2z) XRED(a2w)
    XRED(a3x) XRED(a3y) XRED(a3z) XRED(a3w)
    XRED(ssum)
#undef XRED

    const float inv = (ssum > 0.f) ? (1.0f / ssum) : 0.f;   // empty segment -> 0
    // all lanes now hold identical totals; lane (g,q) stores float4 chunk g of
    // its 16 dims -> one fully-coalesced 1 KB store per wave
    float vx = (g==0) ? a0x : (g==1) ? a1x : (g==2) ? a2x : a3x;
    float vy = (g==0) ? a0y : (g==1) ? a1y : (g==2) ? a2y : a3y;
    float vz = (g==0) ? a0z : (g==1) ? a1z : (g==2) ? a2z : a3z;
    float vw = (g==0) ? a0w : (g==1) ? a1w : (g==2) ? a2w : a3w;
    float4 v; v.x = vx*inv; v.y = vy*inv; v.z = vz*inv; v.w = vw*inv;
    *(float4*)(&rout[(size_t)b * rstride + q * 16 + g * 4]) = v;
}

// ---------------------------------------------------------------------------
// Kernel 4: fused LSTM step via bf16 MFMA. Same verified structure; epilogue
// now uses hw-exp tanh and optionally duplicates h into out[:, :256] (fuses
// the old writeout kernel into the m==M_STEPS-2 call).
// ---------------------------------------------------------------------------
#define LBM 128
#define LBK 64
#define APAD 8
__global__ __launch_bounds__(256, 2) void lstm_mfma_kernel(
    const float* __restrict__ h_in,
    const float* __restrict__ r,
    const unsigned short* __restrict__ ubf,
    const float* __restrict__ bias,
    float* __restrict__ c,
    float* __restrict__ h_out,
    float* __restrict__ hdup)         // if non-null: also write h, row stride 512
{
    __shared__ unsigned short As[LBM][LBK + APAD];

    const int t = threadIdx.x;
    const int w = t >> 6;
    const int lane = t & 63;
    const int m0 = blockIdx.y * LBM;
    const int bx = blockIdx.x;

    f32x16 acc[8];
    #pragma unroll
    for (int et = 0; et < 8; ++et)
        #pragma unroll
        for (int q = 0; q < 16; ++q) acc[et][q] = 0.0f;

    for (int kb = 0; kb < 8; ++kb) {
        const float* A = (kb < 4) ? h_in : r;
        const int ak = (kb & 3) * LBK;
        __syncthreads();
        #pragma unroll
        for (int i = 0; i < 8; ++i) {
            int idx = i * 256 + t;
            int row = idx >> 4, k4 = idx & 15;
            float4 v = *(const float4*)(&A[(size_t)(m0 + row) * DIM + ak + k4 * 4]);
            ushort4 bv;
            bv.x = f2bf(v.x); bv.y = f2bf(v.y); bv.z = f2bf(v.z); bv.w = f2bf(v.w);
            *(ushort4*)(&As[row][k4 * 4]) = bv;
        }
        __syncthreads();
        #pragma unroll
        for (int kc = 0; kc < 4; ++kc) {
            bf16x8 af = *(const bf16x8*)(&As[w * 32 + (lane & 31)][kc * 16 + (lane >> 5) * 8]);
            const int kglob = kb * 4 + kc;
            #pragma unroll
            for (int et = 0; et < 8; ++et) {
                const int g = et >> 1;
                const int nt = g * 8 + bx * 2 + (et & 1);
                bf16x8 bfr = *(const bf16x8*)(&ubf[((size_t)(nt * 32 + kglob) * 64 + lane) * 8]);
                acc[et] = __builtin_amdgcn_mfma_f32_32x32x16_bf16(af, bfr, acc[et], 0, 0, 0);
            }
        }
    }

    const int col32 = lane & 31;
    const int rbase = m0 + w * 32 + 4 * (lane >> 5);
    #pragma unroll
    for (int jh = 0; jh < 2; ++jh) {
        const int col = bx * 64 + jh * 32 + col32;
        const float bi = bias[col];
        const float bf_ = bias[256 + col];
        const float bo = bias[512 + col];
        const float bg = bias[768 + col];
        const f32x16 zi = acc[0 * 2 + jh];
        const f32x16 zf = acc[1 * 2 + jh];
        const f32x16 zo = acc[2 * 2 + jh];
        const f32x16 zg = acc[3 * 2 + jh];
        #pragma unroll
        for (int reg = 0; reg < 16; ++reg) {
            const int row = rbase + (reg & 3) + 8 * (reg >> 2);
            const size_t idx = (size_t)row * DIM + col;
            const float ig = sigmoidf_(zi[reg] + bi);
            const float fg = sigmoidf_(zf[reg] + bf_);
            const float og = sigmoidf_(zo[reg] + bo);
            const float gg = tanh_fast(zg[reg] + bg);
            const float cn = fg * c[idx] + ig * gg;
            c[idx] = cn;
            const float hn = og * tanh_fast(cn);
            h_out[idx] = hn;
            if (hdup) hdup[(size_t)row * 512 + col] = hn;
        }
    }
}

// ---------------------------------------------------------------------------
extern "C" void kernel_launch(void* const* d_in, const int* in_sizes, int n_in,
                              void* d_out, int out_size, void* d_ws, size_t ws_size,
                              hipStream_t stream) {
    const float* x     = (const float*)d_in[0];
    const int*   split = (const int*)d_in[1];
    const float* U     = (const float*)d_in[2];
    const float* bias  = (const float*)d_in[3];
    float* out = (float*)d_out;

    char* ws = (char*)d_ws;
    const size_t lb_bytes  = ((size_t)(NB + 1) * sizeof(int) + 255) & ~(size_t)255;
    const size_t mat_bytes = (size_t)NB * DIM * sizeof(float);   // 16 MB
    int*   lb   = (int*)ws;
    float* h0   = (float*)(ws + lb_bytes);
    float* h1   = (float*)(ws + lb_bytes + mat_bytes);
    float* cbuf = (float*)(ws + lb_bytes + 2 * mat_bytes);
    float* rbuf = (float*)(ws + lb_bytes + 3 * mat_bytes);
    unsigned short* ubf = (unsigned short*)(ws + lb_bytes + 4 * mat_bytes); // 1 MB

    bounds_kernel<<<(NB + 1 + 255) / 256, 256, 0, stream>>>(split, lb);
    uswz_kernel<<<1024, 256, 0, stream>>>(U, ubf);
    hipMemsetAsync(h0, 0, mat_bytes, stream);
    hipMemsetAsync(cbuf, 0, mat_bytes, stream);

    float* h_cur = h0;
    float* h_nxt = h1;
    for (int m = 0; m < M_STEPS; ++m) {
        const bool last = (m == M_STEPS - 1);
        float* rdst   = last ? (out + DIM) : rbuf;
        int    rstrid = last ? (2 * DIM) : DIM;
        attn_kernel<<<NB / 4, 256, 0, stream>>>(x, lb, h_cur, rdst, rstrid);
        if (!last) {
            dim3 grid(4, NB / LBM);
            // the h produced at m == M_STEPS-2 is the h that lands in out[:, :256]
            float* hdup = (m == M_STEPS - 2) ? out : (float*)nullptr;
            lstm_mfma_kernel<<<grid, 256, 0, stream>>>(h_cur, rbuf, ubf, bias, cbuf, h_nxt, hdup);
            float* tmp = h_cur; h_cur = h_nxt; h_nxt = tmp;
        }
    }
}